// Round 1
// baseline (144.438 us; speedup 1.0000x reference)
//
#include <hip/hip_runtime.h>
#include <stdint.h>

#define SS 2048
#define BB 16
#define DD 128
#define DVV 128
#define BQ 32
#define BK 32
#define NTILES (SS / BK)        // 64 k-tiles per batch
#define TILE_HW 4096            // 8 KB tile image = 4096 halfwords

typedef __attribute__((ext_vector_type(8))) short short8;
typedef __attribute__((ext_vector_type(4))) float float4v;

// RTNE float -> bf16 (inputs finite)
__device__ __forceinline__ short f2bf(float f) {
  union { float f; uint32_t u; } x;
  x.f = f;
  uint32_t r = x.u + 0x7fffu + ((x.u >> 16) & 1u);
  return (short)(r >> 16);
}

// key permutation kappa: PV fragment slot (quad, j) <-> key (verified R4/R5)
__device__ __forceinline__ int kappa(int quad, int j) {
  return (j < 4) ? (quad * 4 + j) : (16 + quad * 4 + (j - 4));
}

// ---- preconvert K and V into FRAGMENT-LINEAR images ----
// chunk idx in [0,512): lane l = idx&63 reads 16B at tile_base + idx*16B in attn.
// K image: j = idx>>6 = ks*2+half; content K[half*16 + (l&15)][(ks*4 + (l>>4))*8 + i]
// V image: nt = idx>>6;            content V[kappa(l>>4, i)][nt*16 + (l&15)]  (R5 verbatim)
__global__ __launch_bounds__(256) void conv_kv(
    const float* __restrict__ kg, const float* __restrict__ vg,
    short* __restrict__ kimg, short* __restrict__ vimg) {
  __shared__ short tile[BK][136];
  const int t = blockIdx.x, b = blockIdx.y;
  const float* src_base = (blockIdx.z == 0) ? kg : vg;
  short* out = ((blockIdx.z == 0) ? kimg : vimg) + ((size_t)(b * NTILES + t)) * TILE_HW;
  // phase 1: coalesced fp32 load -> bf16 -> LDS tile
#pragma unroll
  for (int p = 0; p < 2; ++p) {
    const int ch = threadIdx.x + p * 256;  // key*16 + c
    const int key = ch >> 4, c = ch & 15;
    const float* src = src_base + ((size_t)(t * BK + key) * BB + b) * DD + c * 8;
    float4v f0 = *(const float4v*)src;
    float4v f1 = *(const float4v*)(src + 4);
    short8 s;
#pragma unroll
    for (int i = 0; i < 4; ++i) { s[i] = f2bf(f0[i]); s[4 + i] = f2bf(f1[i]); }
    *(short8*)&tile[key][c * 8] = s;
  }
  __syncthreads();
  // phase 2: fragment-linear permuted write (coalesced 16B/lane)
#pragma unroll
  for (int p = 0; p < 2; ++p) {
    const int idx = threadIdx.x + p * 256;
    const int j = idx >> 6, quad = (idx >> 4) & 3, mm = idx & 15;
    short8 s;
    if (blockIdx.z == 0) {
      const int ks = j >> 1, half = j & 1;
      s = *(const short8*)&tile[half * 16 + mm][(ks * 4 + quad) * 8];
    } else {
#pragma unroll
      for (int jj = 0; jj < 8; ++jj) s[jj] = tile[kappa(quad, jj)][j * 16 + mm];
    }
    *(short8*)(out + idx * 8) = s;
  }
}

// ---- attention: barrier-free main loop, fragments straight from L2 ----
// 4 waves = (tile-parity, q-half); additive partials, LDS combine at end only.
__global__ __launch_bounds__(256, 4) void attn_fwd(
    const float* __restrict__ qg, const short* __restrict__ kimg,
    const short* __restrict__ vimg, float* __restrict__ og) {
  __shared__ __align__(16) float cw[128 * 36];  // 18.4 KB combine scratch

  const int tid   = threadIdx.x;
  const int wave  = tid >> 6;
  const int qwave = wave & 1;   // q-row group (0: rows 0..15, 1: rows 16..31)
  const int tpar  = wave >> 1;  // tile parity this wave computes
  const int lane  = tid & 63;
  const int m     = lane & 15;
  const int quad  = lane >> 4;
  const int bid   = blockIdx.x;
  // XCD-local dispatch: xcd = bid&7 serves b in {2*xcd, 2*xcd+1} -> 2 MB of
  // K/V images per XCD L2 (4 MB). qt quadruple at CU stride 256 sums to a
  // constant: {63-g, g, 47-g, 16+g} -> exact per-CU load balance.
  const int g  = (bid >> 4) & 15;
  const int ph = bid >> 8;
  const int b  = ((bid & 7) << 1) | ((bid >> 3) & 1);
  const int qt = (ph == 0) ? 63 - g : (ph == 1) ? g : (ph == 2) ? 47 - g : 16 + g;
  const int qw = qt * BQ + qwave * 16;
  const int qrow = qw + m;

  // Q fragments (B operand: lane&15 = q-row), 1/sqrt(D)*log2(e) folded
  const float cscale = 0.08838834764831845f * 1.4426950408889634f;
  short8 qfrag[4];
#pragma unroll
  for (int ks = 0; ks < 4; ++ks) {
    const float* qp = qg + ((size_t)qrow * BB + b) * DD + ks * 32 + quad * 8;
    float4v f0 = *(const float4v*)qp;
    float4v f1 = *(const float4v*)(qp + 4);
    short8 f;
#pragma unroll
    for (int i = 0; i < 4; ++i) { f[i] = f2bf(f0[i] * cscale); f[4 + i] = f2bf(f1[i] * cscale); }
    qfrag[ks] = f;
  }

  float4v oacc[8];
#pragma unroll
  for (int i = 0; i < 8; ++i) oacc[i] = (float4v){0.f, 0.f, 0.f, 0.f};
  float psum = 0.f;

  const short* kt = kimg + (size_t)b * NTILES * TILE_HW + lane * 8;
  const short* vt = vimg + (size_t)b * NTILES * TILE_HW + lane * 8;
  const int ntile = qt + 1;

  for (int t = tpar; t < ntile; t += 2) {
    const short* kp = kt + (size_t)t * TILE_HW;
    const short* vp = vt + (size_t)t * TILE_HW;

    // ---- S = K·Q^T, fragments direct from global (coalesced b128) ----
    float4v s0 = {0.f, 0.f, 0.f, 0.f}, s1 = {0.f, 0.f, 0.f, 0.f};
#pragma unroll
    for (int ks = 0; ks < 4; ++ks) {
      short8 kf0 = *(const short8*)(kp + (ks * 2 + 0) * 512);
      short8 kf1 = *(const short8*)(kp + (ks * 2 + 1) * 512);
      s0 = __builtin_amdgcn_mfma_f32_16x16x32_bf16(kf0, qfrag[ks], s0, 0, 0, 0);
      s1 = __builtin_amdgcn_mfma_f32_16x16x32_bf16(kf1, qfrag[ks], s1, 0, 0, 0);
    }
    float sv[8];
#pragma unroll
    for (int rr = 0; rr < 4; ++rr) { sv[rr] = s0[rr]; sv[4 + rr] = s1[rr]; }

    const int kt0 = t * BK;
    if (kt0 + BK - 1 > qw) {  // wave-uniform: only diagonal tiles
#pragma unroll
      for (int j = 0; j < 8; ++j)
        if (kt0 + kappa(quad, j) > qrow) sv[j] = -1e30f;
    }

    // ---- fixed-reference softmax: p = exp2(s); packed RTNE cvt; exact psum
    //      (bit-identical to f2bf path: v_cvt_pk_bf16_f32 is RTNE) ----
    union { short8 s8; uint32_t w[4]; } pf;
#pragma unroll
    for (int jp = 0; jp < 4; ++jp) {
      float p0 = exp2f(sv[2 * jp]);
      float p1 = exp2f(sv[2 * jp + 1]);
      uint32_t w;
      asm("v_cvt_pk_bf16_f32 %0, %1, %2" : "=v"(w) : "v"(p0), "v"(p1));
      pf.w[jp] = w;
      union { uint32_t u; float f; } lo, hi;
      lo.u = w << 16;
      hi.u = w & 0xffff0000u;
      psum += lo.f;
      psum += hi.f;
    }
    const short8 pfrag = pf.s8;

    // ---- PV, V fragments direct from global (image already frag-linear) ----
#pragma unroll
    for (int nt = 0; nt < 8; ++nt) {
      short8 vf = *(const short8*)(vp + nt * 512);
      oacc[nt] = __builtin_amdgcn_mfma_f32_16x16x32_bf16(pfrag, vf, oacc[nt], 0, 0, 0);
    }
  }

  // ---- combine odd-parity partials into even-parity waves (additive) ----
  if (tpar == 1) {
    float* p = cw + (size_t)(qwave * 64 + lane) * 36;
#pragma unroll
    for (int nt = 0; nt < 8; ++nt) *(float4v*)(p + nt * 4) = oacc[nt];
    p[32] = psum;
  }
  __syncthreads();
  if (tpar == 0) {
    const float* p = cw + (size_t)(qwave * 64 + lane) * 36;
#pragma unroll
    for (int nt = 0; nt < 8; ++nt) oacc[nt] += *(const float4v*)(p + nt * 4);
    psum += p[32];

    // ---- epilogue (verbatim R5) ----
    float l = psum;
    l += __shfl_xor(l, 16, 64);
    l += __shfl_xor(l, 32, 64);
    const float linv = 1.0f / l;
    float l4[4];
#pragma unroll
    for (int rr = 0; rr < 4; ++rr) l4[rr] = __shfl(linv, quad * 4 + rr, 64);
#pragma unroll
    for (int rr = 0; rr < 4; ++rr) {
      const int qgl = qw + quad * 4 + rr;
      float* op = og + ((size_t)qgl * BB + b) * DVV + m;
#pragma unroll
      for (int nt = 0; nt < 8; ++nt) op[nt * 16] = oacc[nt][rr] * l4[rr];
    }
  }
}

extern "C" void kernel_launch(void* const* d_in, const int* in_sizes, int n_in,
                              void* d_out, int out_size, void* d_ws, size_t ws_size,
                              hipStream_t stream) {
  const float* q = (const float*)d_in[0];
  const float* k = (const float*)d_in[1];
  const float* v = (const float*)d_in[2];
  float* out = (float*)d_out;
  short* kimg = (short*)d_ws;
  short* vimg = kimg + (size_t)BB * NTILES * TILE_HW;  // 8.39 MB each

  conv_kv<<<dim3(NTILES, BB, 2), 256, 0, stream>>>(k, v, kimg, vimg);
  attn_fwd<<<dim3(SS / BQ * BB), 256, 0, stream>>>(q, kimg, vimg, out);
}